// Round 11
// baseline (147.973 us; speedup 1.0000x reference)
//
#include <hip/hip_runtime.h>

// Problem constants (fixed by setup_inputs: B=2,C=32,H=128,W=240, max_disp=192 -> D=48)
constexpr int B  = 2;
constexpr int C  = 32;
constexpr int H  = 128;
constexpr int W  = 240;
constexpr int D  = 48;
constexpr int C2 = 2 * C;            // 64 output channels
constexpr int W4 = W / 4;            // 60 float4 per row
constexpr int QPS = H * W4;          // 7680 quads per (plane,d) slice
constexpr int HROWS = 64;            // rows per block (half plane)
constexpr int QPB = HROWS * W4;      // 3840 quads per half-plane
constexpr int BLOCK = 256;
constexpr int KS = QPB / BLOCK;      // 15 quads per thread per slice
constexpr int NDQ = D / 4;           // 12 d-quads
constexpr int GRID = B * C2 * NDQ * 2;  // 3072 blocks

// native vector type for __builtin_nontemporal_store (HIP_vector_type is rejected)
typedef float nfloat4 __attribute__((ext_vector_type(4)));

__device__ __forceinline__ void nt_store(float4* p, float x, float y, float z, float w)
{
    nfloat4 v = { x, y, z, w };
    __builtin_nontemporal_store(v, reinterpret_cast<nfloat4*>(p));
}

__global__ __launch_bounds__(256)
void cost_volume_kernel(const float* __restrict__ left,
                        const float* __restrict__ right,
                        float4* __restrict__ out)
{
    // R9's contiguous-output mapping, but register-preloaded (no LDS, no
    // per-iteration waits, no occupancy cliff): the unconfounded test of
    // write-front contiguity. Consecutive bid -> consecutive 60 KB regions.
    int bid   = blockIdx.x;
    int rh    = bid & 1;
    int t     = bid >> 1;
    int dq    = t % NDQ;             // d = 4*dq + dd, dd in [0,4)
    int plane = t / NDQ;             // 0..127
    int c2    = plane & (C2 - 1);
    int b     = plane >> 6;

    const float* baseimg = (c2 < C)
        ? left  + (size_t)((b * C + c2)       * H) * W
        : right + (size_t)((b * C + (c2 - C)) * H) * W;
    const float4* img = reinterpret_cast<const float4*>(baseimg + rh * HROWS * W);

    float4* outbase = out + ((size_t)plane * D + 4 * dq) * QPS + rh * QPB;

    if (c2 < C) {
        // ---- left half: preload 15 quads, then 60 pure nt stores ----
        // mask: elem j at d=4dq+dd unmasked iff w4*4 + j >= 4dq+dd <=> m+j >= dd
        float4 P[KS];
        int    m[KS];
#pragma unroll
        for (int k = 0; k < KS; ++k) {
            int qi  = (int)threadIdx.x + k * BLOCK;
            int row = qi / W4;
            int w4  = qi - row * W4;
            m[k] = (w4 - dq) * 4;
            P[k] = img[qi];
        }
#pragma unroll
        for (int dd = 0; dd < 4; ++dd) {
#pragma unroll
            for (int k = 0; k < KS; ++k) {
                int qi = (int)threadIdx.x + k * BLOCK;
                nt_store(outbase + dd * QPS + qi,
                         (m[k] + 0 >= dd) ? P[k].x : 0.0f,
                         (m[k] + 1 >= dd) ? P[k].y : 0.0f,
                         (m[k] + 2 >= dd) ? P[k].z : 0.0f,
                         (m[k] + 3 >= dd) ? P[k].w : 0.0f);
            }
        }
    } else {
        // ---- right half: preload 30 quads (Hi/Lo per k), then 60 stores ----
        // All 4 dd of group dq share the same 2 quads: Hi=w4-dq, Lo=Hi-1.
        // win[4+j-dd] selects elem j (compile-time after unroll).
        // Clamped (<0) quad indices feed only mask-zeroed elements:
        // an element sourced from a clamped quad has true source index
        // w0+j-d < 0 <=> w0+j < d <=> masked (same proof as R9).
        float4 Pm[KS], Pl[KS];
        int    m[KS];
#pragma unroll
        for (int k = 0; k < KS; ++k) {
            int qi  = (int)threadIdx.x + k * BLOCK;
            int row = qi / W4;
            int w4  = qi - row * W4;
            int hq  = w4 - dq;
            int lq  = hq - 1;
            int rowbase = row * W4;
            m[k]  = (w4 - dq) * 4;
            Pm[k] = img[rowbase + (hq < 0 ? 0 : hq)];
            Pl[k] = img[rowbase + (lq < 0 ? 0 : lq)];
        }
#pragma unroll
        for (int dd = 0; dd < 4; ++dd) {
#pragma unroll
            for (int k = 0; k < KS; ++k) {
                int qi = (int)threadIdx.x + k * BLOCK;
                float win[8] = { Pl[k].x, Pl[k].y, Pl[k].z, Pl[k].w,
                                 Pm[k].x, Pm[k].y, Pm[k].z, Pm[k].w };
                nt_store(outbase + dd * QPS + qi,
                         (m[k] + 0 >= dd) ? win[4 + 0 - dd] : 0.0f,
                         (m[k] + 1 >= dd) ? win[4 + 1 - dd] : 0.0f,
                         (m[k] + 2 >= dd) ? win[4 + 2 - dd] : 0.0f,
                         (m[k] + 3 >= dd) ? win[4 + 3 - dd] : 0.0f);
            }
        }
    }
}

extern "C" void kernel_launch(void* const* d_in, const int* in_sizes, int n_in,
                              void* d_out, int out_size, void* d_ws, size_t ws_size,
                              hipStream_t stream)
{
    const float* left  = (const float*)d_in[0];
    const float* right = (const float*)d_in[1];
    float4* out = (float4*)d_out;

    cost_volume_kernel<<<GRID, BLOCK, 0, stream>>>(left, right, out);
}